// Round 9
// baseline (472.630 us; speedup 1.0000x reference)
//
#include <hip/hip_runtime.h>

// ---------------------------------------------------------------------------
// PINN residual via MFMA (gfx950) — R9: mt=2 (32 cols/wave) to halve per-point
// B-frag LDS traffic (R8 analysis: LDS pipe ~55% busy, W re-read 12x/chunk).
// Block 512 = 8 waves (2/SIMD); each ds_read_b128 of W feeds 2 MFMAs.
// Transition staged in two 16-row half-passes -> stage stays 2.5 KB/wave.
// Stage row stride 80 B (16-aligned) -> A-frag read = 1 ds_read_b128.
// Chunk = 64 points -> 256 B aligned output (fixes R8 write amplification).
// Numerics (validated R7): A 2-plane fp16 (1, x512), W 2-plane fp16,
// 3 products: C0=a0w0; C1=a0w1+a1w0; z=C0+C1/512 (+bias on ch0).
// ---------------------------------------------------------------------------

using half8 = __attribute__((ext_vector_type(8))) _Float16;
using half4 = __attribute__((ext_vector_type(4))) _Float16;
using f32x4 = __attribute__((ext_vector_type(4))) float;

#define LW      44800     // bytes of pre-split W per layer (2 planes)
#define ZOFF    134400    // 16-byte zero block (B-frag tail, lanes>=16)
#define STGOFF  134416
#define STGW    2560      // per-wave: 2 planes x 16 rows x 40 halves
#define PLANEB  1280      // plane stride bytes
#define SMEM_BYTES 154896 // 134416 + 8*2560

union U8 { uint4 u; half8 h; };
union U4 { uint2 u; half4 h; };

static __device__ __forceinline__ float fast_tanh(float z) {
    float e = __expf(2.0f * z);
    return 1.0f - 2.0f * __builtin_amdgcn_rcpf(e + 1.0f);
}

static __device__ __forceinline__ void split2(float v, _Float16& h0, _Float16& h1) {
    h0 = (_Float16)v;
    h1 = (_Float16)((v - (float)h0) * 512.0f);
}

// --------------------------- W pre-split kernel ----------------------------
__global__ void prep_w(const float* __restrict__ W2, const float* __restrict__ W3,
                       const float* __restrict__ W4, unsigned short* __restrict__ ws) {
    int bid = blockIdx.x;
    int l = bid / 28, rem = bid % 28, kt = rem / 7, jt = rem % 7;
    const float* W = (l == 0) ? W2 : (l == 1) ? W3 : W4;
    int lane = threadIdx.x;
    int c = lane & 15, q = lane >> 4;
    int j = 16 * jt + c;
    if (kt < 3) {
        for (int s = 0; s < 2; ++s)
            for (int i = 0; i < 8; ++i) {
                int k = 32 * kt + 8 * q + i;               // <= 95
                float w = (j < 100) ? W[j * 100 + k] : 0.0f;
                _Float16 h0 = (_Float16)w;
                _Float16 val = (s == 0) ? h0 : (_Float16)((w - (float)h0) * 512.0f);
                ws[(l*LW + kt*14336 + jt*2048 + s*1024 + lane*16 + i*2) >> 1] =
                    __builtin_bit_cast(unsigned short, val);
            }
    } else if (lane < 16) {                                 // tail: k=96..99
        for (int s = 0; s < 2; ++s)
            for (int i = 0; i < 4; ++i) {
                int k = 96 + i;
                float w = (j < 100) ? W[j * 100 + k] : 0.0f;
                _Float16 h0 = (_Float16)w;
                _Float16 val = (s == 0) ? h0 : (_Float16)((w - (float)h0) * 512.0f);
                ws[(l*LW + 43008 + jt*256 + s*128 + lane*8 + i*2) >> 1] =
                    __builtin_bit_cast(unsigned short, val);
            }
    }
}

// ------------------------------- main kernel -------------------------------
__global__ void __launch_bounds__(512, 2) pinn_mfma(
    const float* __restrict__ x,  const float* __restrict__ t,
    const float* __restrict__ W1, const float* __restrict__ b1,
    const float* __restrict__ b2, const float* __restrict__ b3,
    const float* __restrict__ b4,
    const float* __restrict__ W5, const float* __restrict__ b5,
    const char* __restrict__ ws, float* __restrict__ out,
    int N, int nchunks)
{
    extern __shared__ char smem[];
    const int tid  = threadIdx.x;
    const int w    = tid >> 6;           // wave id 0..7
    const int lane = tid & 63;
    const int c15  = lane & 15;
    const int q    = lane >> 4;

    // stage all pre-split W into LDS (134400 B = 8400 uint4)
    for (int it = 0; it < 17; ++it) {
        int idx = tid + it * 512;
        if (idx < 8400) ((uint4*)smem)[idx] = ((const uint4*)ws)[idx];
    }
    if (tid < 4) *(unsigned*)(smem + ZOFF + tid * 4) = 0u;
    __syncthreads();

    char* stg = smem + STGOFF + w * STGW;   // fp16 planes [p:2][n:16][kk:40]

    half8 a0[2][3], a1[2][3];            // A planes per mt, ktile
    half4 a0t[2],   a1t[2];              // K-tail frags (16x16x16)
    f32x4 c0[7][2], c1[7][2];

    for (int chunk = blockIdx.x; chunk < nchunks; chunk += gridDim.x) {
        const int colbase = chunk * 256 + w * 32;

        // ---------------- layer 1: direct A-frag build ----------------
        #pragma unroll
        for (int mt = 0; mt < 2; ++mt) {
            int col = colbase + 16 * mt + c15;
            int pt = col >> 2, ch = col & 3;
            int ptc = (pt < N) ? pt : (N - 1);
            float xv = x[ptc], tv = t[ptc];
            #pragma unroll
            for (int kt = 0; kt < 3; ++kt) {
                half8 v0, v1;
                #pragma unroll
                for (int i = 0; i < 8; ++i) {
                    int j = 32 * kt + 8 * q + i;           // <= 95
                    float w0 = W1[2*j], w1 = W1[2*j+1], bb = b1[j];
                    float p = fmaf(w0, xv, fmaf(w1, tv, bb));
                    float a = fast_tanh(p);
                    float s = 1.0f - a * a;
                    float v = (ch == 0) ? a : (ch == 1) ? s * w1
                             : (ch == 2) ? s * w0 : -2.0f * a * s * w0 * w0;
                    _Float16 h0, h1; split2(v, h0, h1);
                    v0[i] = h0; v1[i] = h1;
                }
                a0[mt][kt] = v0; a1[mt][kt] = v1;
            }
            half4 t0 = {0, 0, 0, 0}, t1 = {0, 0, 0, 0};
            if (q == 0) {
                #pragma unroll
                for (int i = 0; i < 4; ++i) {
                    int j = 96 + i;
                    float w0 = W1[2*j], w1 = W1[2*j+1], bb = b1[j];
                    float p = fmaf(w0, xv, fmaf(w1, tv, bb));
                    float a = fast_tanh(p);
                    float s = 1.0f - a * a;
                    float v = (ch == 0) ? a : (ch == 1) ? s * w1
                             : (ch == 2) ? s * w0 : -2.0f * a * s * w0 * w0;
                    _Float16 h0, h1; split2(v, h0, h1);
                    t0[i] = h0; t1[i] = h1;
                }
            }
            a0t[mt] = t0; a1t[mt] = t1;
        }

        // ---------------- 3 hidden GEMMs + transitions ----------------
        for (int l = 0; l < 3; ++l) {
            const char* WL = smem + l * LW;
            const float* BL = (l == 0) ? b2 : (l == 1) ? b3 : b4;

            #pragma unroll
            for (int jt = 0; jt < 7; ++jt)
                #pragma unroll
                for (int mt = 0; mt < 2; ++mt) {
                    c0[jt][mt] = (f32x4){0.f, 0.f, 0.f, 0.f};
                    c1[jt][mt] = (f32x4){0.f, 0.f, 0.f, 0.f};
                }

            #pragma unroll
            for (int kt = 0; kt < 3; ++kt)
                #pragma unroll
                for (int jt = 0; jt < 7; ++jt) {
                    U8 b0u, b1u;
                    b0u.u = *(const uint4*)(WL + kt*14336 + jt*2048 + lane*16);
                    b1u.u = *(const uint4*)(WL + kt*14336 + jt*2048 + 1024 + lane*16);
                    #pragma unroll
                    for (int mt = 0; mt < 2; ++mt) {
                        c0[jt][mt] = __builtin_amdgcn_mfma_f32_16x16x32_f16(a0[mt][kt], b0u.h, c0[jt][mt], 0, 0, 0);
                        c1[jt][mt] = __builtin_amdgcn_mfma_f32_16x16x32_f16(a0[mt][kt], b1u.h, c1[jt][mt], 0, 0, 0);
                        c1[jt][mt] = __builtin_amdgcn_mfma_f32_16x16x32_f16(a1[mt][kt], b0u.h, c1[jt][mt], 0, 0, 0);
                    }
                }
            #pragma unroll
            for (int jt = 0; jt < 7; ++jt) {               // K-tail (k=96..99)
                int toff  = (lane < 16) ? (l*LW + 43008 + jt*256 + lane*8) : ZOFF;
                int toff1 = (lane < 16) ? (toff + 128) : ZOFF;
                U4 b0u, b1u;
                b0u.u = *(const uint2*)(smem + toff);
                b1u.u = *(const uint2*)(smem + toff1);
                #pragma unroll
                for (int mt = 0; mt < 2; ++mt) {
                    c0[jt][mt] = __builtin_amdgcn_mfma_f32_16x16x16f16(a0t[mt], b0u.h, c0[jt][mt], 0, 0, 0);
                    c1[jt][mt] = __builtin_amdgcn_mfma_f32_16x16x16f16(a0t[mt], b1u.h, c1[jt][mt], 0, 0, 0);
                    c1[jt][mt] = __builtin_amdgcn_mfma_f32_16x16x16f16(a1t[mt], b0u.h, c1[jt][mt], 0, 0, 0);
                }
            }

            if (l < 2) {
                // ---- transition: two 16-row half-passes per kc tile ----
                #pragma unroll
                for (int kc = 0; kc < 4; ++kc) {
                    int njt = (kc < 3) ? 2 : 1;
                    #pragma unroll
                    for (int mtt = 0; mtt < 2; ++mtt) {
                        #pragma unroll
                        for (int jj = 0; jj < 2; ++jj) {
                            if (jj >= njt) continue;
                            int jt = 2 * kc + jj;
                            int kk = 16 * jj + c15;
                            int j  = 16 * jt + c15;
                            float bj = BL[(j < 100) ? j : 99];
                            float z0 = c0[jt][mtt][0] + c1[jt][mtt][0] * (1.0f/512.0f) + bj;
                            float z1 = c0[jt][mtt][1] + c1[jt][mtt][1] * (1.0f/512.0f);
                            float z2 = c0[jt][mtt][2] + c1[jt][mtt][2] * (1.0f/512.0f);
                            float z3 = c0[jt][mtt][3] + c1[jt][mtt][3] * (1.0f/512.0f);
                            float a = fast_tanh(z0);
                            float s = 1.0f - a * a;
                            float v[4];
                            v[0] = a; v[1] = s * z1; v[2] = s * z2;
                            v[3] = fmaf(-2.0f * a * s * z2, z2, s * z3);
                            #pragma unroll
                            for (int r = 0; r < 4; ++r) {
                                _Float16 h0, h1; split2(v[r], h0, h1);
                                _Float16* bp = (_Float16*)(stg) + (4 * q + r) * 40 + kk;
                                bp[0]   = h0;
                                bp[640] = h1;    // plane 1 (+1280 B)
                            }
                        }
                        // read this half's A-frags for kt = kc (wave-private)
                        if (kc < 3) {
                            const char* rb = stg + c15 * 80 + 16 * q;
                            U8 u;
                            u.u = *(const uint4*)(rb);            a0[mtt][kc] = u.h;
                            u.u = *(const uint4*)(rb + PLANEB);   a1[mtt][kc] = u.h;
                        } else {
                            U4 u;
                            if (q == 0) {
                                const char* rb = stg + c15 * 80;
                                u.u = *(const uint2*)(rb);            a0t[mtt] = u.h;
                                u.u = *(const uint2*)(rb + PLANEB);   a1t[mtt] = u.h;
                            } else {
                                a0t[mtt] = (half4){0,0,0,0}; a1t[mtt] = (half4){0,0,0,0};
                            }
                        }
                    }
                }
            } else {
                // ---- layer-4 bias+nonlinearity + layer-5 + NLS residual ----
                #pragma unroll
                for (int mt = 0; mt < 2; ++mt) {
                    float p00 = 0.f, p01 = 0.f, p03 = 0.f;   // W5 row 0 (real)
                    float p10 = 0.f, p11 = 0.f, p13 = 0.f;   // W5 row 1 (imag)
                    #pragma unroll
                    for (int jt = 0; jt < 7; ++jt) {
                        int j = 16 * jt + c15;
                        int j2 = (j < 100) ? j : 99;
                        float m = (j < 100) ? 1.0f : 0.0f;
                        float bj = BL[j2];
                        float w50 = W5[j2] * m, w51 = W5[100 + j2] * m;
                        float z0 = c0[jt][mt][0] + c1[jt][mt][0] * (1.0f/512.0f) + bj;
                        float z1 = c0[jt][mt][1] + c1[jt][mt][1] * (1.0f/512.0f);
                        float z2 = c0[jt][mt][2] + c1[jt][mt][2] * (1.0f/512.0f);
                        float z3 = c0[jt][mt][3] + c1[jt][mt][3] * (1.0f/512.0f);
                        float a = fast_tanh(z0);
                        float s = 1.0f - a * a;
                        float v0 = a, v1 = s * z1;
                        float v3 = fmaf(-2.0f * a * s * z2, z2, s * z3);
                        p00 = fmaf(w50, v0, p00);
                        p01 = fmaf(w50, v1, p01);
                        p03 = fmaf(w50, v3, p03);
                        p10 = fmaf(w51, v0, p10);
                        p11 = fmaf(w51, v1, p11);
                        p13 = fmaf(w51, v3, p13);
                    }
                    #pragma unroll
                    for (int m = 1; m <= 8; m <<= 1) {
                        p00 += __shfl_xor(p00, m, 64);
                        p01 += __shfl_xor(p01, m, 64);
                        p03 += __shfl_xor(p03, m, 64);
                        p10 += __shfl_xor(p10, m, 64);
                        p11 += __shfl_xor(p11, m, 64);
                        p13 += __shfl_xor(p13, m, 64);
                    }
                    int pt = chunk * 64 + w * 8 + 4 * mt + q;
                    if (c15 == 0 && pt < N) {
                        float ur = p00 + b5[0], ui = p10 + b5[1];
                        float mag2 = ur * ur + ui * ui;
                        float fr = fmaf(mag2, ur, fmaf(0.5f, p03, -p11));
                        float fi = fmaf(mag2, ui, fmaf(0.5f, p13,  p01));
                        out[pt]     = fr;
                        out[N + pt] = fi;
                    }
                }
            }
        }
    }
}

extern "C" void kernel_launch(void* const* d_in, const int* in_sizes, int n_in,
                              void* d_out, int out_size, void* d_ws, size_t ws_size,
                              hipStream_t stream) {
    const float* x  = (const float*)d_in[0];
    const float* t  = (const float*)d_in[1];
    const float* W1 = (const float*)d_in[2];
    const float* b1 = (const float*)d_in[3];
    const float* W2 = (const float*)d_in[4];
    const float* b2 = (const float*)d_in[5];
    const float* W3 = (const float*)d_in[6];
    const float* b3 = (const float*)d_in[7];
    const float* W4 = (const float*)d_in[8];
    const float* b4 = (const float*)d_in[9];
    const float* W5 = (const float*)d_in[10];
    const float* b5 = (const float*)d_in[11];
    float* out = (float*)d_out;
    const int N = in_sizes[0];
    const int nchunks = (N + 63) / 64;       // 256 cols = 64 points per chunk

    (void)hipFuncSetAttribute((const void*)pinn_mfma,
                              hipFuncAttributeMaxDynamicSharedMemorySize, SMEM_BYTES);

    prep_w<<<84, 64, 0, stream>>>(W2, W3, W4, (unsigned short*)d_ws);
    pinn_mfma<<<256, 512, SMEM_BYTES, stream>>>(x, t, W1, b1, b2, b3, b4, W5, b5,
                                                (const char*)d_ws, out, N, nchunks);
}

// Round 10
// 468.900 us; speedup vs baseline: 1.0080x; 1.0080x over previous
//
#include <hip/hip_runtime.h>

// ---------------------------------------------------------------------------
// PINN residual via MFMA (gfx950) — R10: R9 (mt=2) + pinned waves_per_eu(2,2).
// R9 failed because __launch_bounds__(512,2) only sets a MINIMUM of 2
// waves/EU: the compiler targeted 4 waves/EU -> 128 VGPRs -> ~24 MB of
// scratch spills (WRITE_SIZE 26.6 MB). LDS (154.9 KB) caps at 1 block/CU
// anyway, so pin exactly 2 waves/EU -> 256-VGPR budget, no spills.
// Per wave: 32 cols (mt=2) so each ds_read_b128 of W feeds 2 MFMAs (halves
// the per-point B-frag LDS traffic vs R8). Transition in two 16-row
// half-passes keeps the stage at 2.5 KB/wave. Chunk = 64 points.
// Numerics (validated R7): A 2-plane fp16 (1, x512), W 2-plane fp16,
// 3 products: C0=a0w0; C1=a0w1+a1w0; z=C0+C1/512 (+bias on ch0).
// ---------------------------------------------------------------------------

using half8 = __attribute__((ext_vector_type(8))) _Float16;
using half4 = __attribute__((ext_vector_type(4))) _Float16;
using f32x4 = __attribute__((ext_vector_type(4))) float;

#define LW      44800     // bytes of pre-split W per layer (2 planes)
#define ZOFF    134400    // 16-byte zero block (B-frag tail, lanes>=16)
#define STGOFF  134416
#define STGW    2560      // per-wave: 2 planes x 16 rows x 40 halves
#define PLANEB  1280      // plane stride bytes
#define SMEM_BYTES 154896 // 134416 + 8*2560

union U8 { uint4 u; half8 h; };
union U4 { uint2 u; half4 h; };

static __device__ __forceinline__ float fast_tanh(float z) {
    float e = __expf(2.0f * z);
    return 1.0f - 2.0f * __builtin_amdgcn_rcpf(e + 1.0f);
}

static __device__ __forceinline__ void split2(float v, _Float16& h0, _Float16& h1) {
    h0 = (_Float16)v;
    h1 = (_Float16)((v - (float)h0) * 512.0f);
}

// --------------------------- W pre-split kernel ----------------------------
__global__ void prep_w(const float* __restrict__ W2, const float* __restrict__ W3,
                       const float* __restrict__ W4, unsigned short* __restrict__ ws) {
    int bid = blockIdx.x;
    int l = bid / 28, rem = bid % 28, kt = rem / 7, jt = rem % 7;
    const float* W = (l == 0) ? W2 : (l == 1) ? W3 : W4;
    int lane = threadIdx.x;
    int c = lane & 15, q = lane >> 4;
    int j = 16 * jt + c;
    if (kt < 3) {
        for (int s = 0; s < 2; ++s)
            for (int i = 0; i < 8; ++i) {
                int k = 32 * kt + 8 * q + i;               // <= 95
                float w = (j < 100) ? W[j * 100 + k] : 0.0f;
                _Float16 h0 = (_Float16)w;
                _Float16 val = (s == 0) ? h0 : (_Float16)((w - (float)h0) * 512.0f);
                ws[(l*LW + kt*14336 + jt*2048 + s*1024 + lane*16 + i*2) >> 1] =
                    __builtin_bit_cast(unsigned short, val);
            }
    } else if (lane < 16) {                                 // tail: k=96..99
        for (int s = 0; s < 2; ++s)
            for (int i = 0; i < 4; ++i) {
                int k = 96 + i;
                float w = (j < 100) ? W[j * 100 + k] : 0.0f;
                _Float16 h0 = (_Float16)w;
                _Float16 val = (s == 0) ? h0 : (_Float16)((w - (float)h0) * 512.0f);
                ws[(l*LW + 43008 + jt*256 + s*128 + lane*8 + i*2) >> 1] =
                    __builtin_bit_cast(unsigned short, val);
            }
    }
}

// ------------------------------- main kernel -------------------------------
__global__ void __launch_bounds__(512)
__attribute__((amdgpu_waves_per_eu(2, 2))) pinn_mfma(
    const float* __restrict__ x,  const float* __restrict__ t,
    const float* __restrict__ W1, const float* __restrict__ b1,
    const float* __restrict__ b2, const float* __restrict__ b3,
    const float* __restrict__ b4,
    const float* __restrict__ W5, const float* __restrict__ b5,
    const char* __restrict__ ws, float* __restrict__ out,
    int N, int nchunks)
{
    extern __shared__ char smem[];
    const int tid  = threadIdx.x;
    const int w    = tid >> 6;           // wave id 0..7
    const int lane = tid & 63;
    const int c15  = lane & 15;
    const int q    = lane >> 4;

    // stage all pre-split W into LDS (134400 B = 8400 uint4)
    for (int it = 0; it < 17; ++it) {
        int idx = tid + it * 512;
        if (idx < 8400) ((uint4*)smem)[idx] = ((const uint4*)ws)[idx];
    }
    if (tid < 4) *(unsigned*)(smem + ZOFF + tid * 4) = 0u;
    __syncthreads();

    char* stg = smem + STGOFF + w * STGW;   // fp16 planes [p:2][n:16][kk:40]

    half8 a0[2][3], a1[2][3];            // A planes per mt, ktile
    half4 a0t[2],   a1t[2];              // K-tail frags (16x16x16)
    f32x4 c0[7][2], c1[7][2];

    for (int chunk = blockIdx.x; chunk < nchunks; chunk += gridDim.x) {
        const int colbase = chunk * 256 + w * 32;

        // ---------------- layer 1: direct A-frag build ----------------
        #pragma unroll
        for (int mt = 0; mt < 2; ++mt) {
            int col = colbase + 16 * mt + c15;
            int pt = col >> 2, ch = col & 3;
            int ptc = (pt < N) ? pt : (N - 1);
            float xv = x[ptc], tv = t[ptc];
            #pragma unroll
            for (int kt = 0; kt < 3; ++kt) {
                half8 v0, v1;
                #pragma unroll
                for (int i = 0; i < 8; ++i) {
                    int j = 32 * kt + 8 * q + i;           // <= 95
                    float w0 = W1[2*j], w1 = W1[2*j+1], bb = b1[j];
                    float p = fmaf(w0, xv, fmaf(w1, tv, bb));
                    float a = fast_tanh(p);
                    float s = 1.0f - a * a;
                    float v = (ch == 0) ? a : (ch == 1) ? s * w1
                             : (ch == 2) ? s * w0 : -2.0f * a * s * w0 * w0;
                    _Float16 h0, h1; split2(v, h0, h1);
                    v0[i] = h0; v1[i] = h1;
                }
                a0[mt][kt] = v0; a1[mt][kt] = v1;
            }
            half4 t0 = {0, 0, 0, 0}, t1 = {0, 0, 0, 0};
            if (q == 0) {
                #pragma unroll
                for (int i = 0; i < 4; ++i) {
                    int j = 96 + i;
                    float w0 = W1[2*j], w1 = W1[2*j+1], bb = b1[j];
                    float p = fmaf(w0, xv, fmaf(w1, tv, bb));
                    float a = fast_tanh(p);
                    float s = 1.0f - a * a;
                    float v = (ch == 0) ? a : (ch == 1) ? s * w1
                             : (ch == 2) ? s * w0 : -2.0f * a * s * w0 * w0;
                    _Float16 h0, h1; split2(v, h0, h1);
                    t0[i] = h0; t1[i] = h1;
                }
            }
            a0t[mt] = t0; a1t[mt] = t1;
        }

        // ---------------- 3 hidden GEMMs + transitions ----------------
        for (int l = 0; l < 3; ++l) {
            const char* WL = smem + l * LW;
            const float* BL = (l == 0) ? b2 : (l == 1) ? b3 : b4;

            #pragma unroll
            for (int jt = 0; jt < 7; ++jt)
                #pragma unroll
                for (int mt = 0; mt < 2; ++mt) {
                    c0[jt][mt] = (f32x4){0.f, 0.f, 0.f, 0.f};
                    c1[jt][mt] = (f32x4){0.f, 0.f, 0.f, 0.f};
                }

            #pragma unroll
            for (int kt = 0; kt < 3; ++kt)
                #pragma unroll
                for (int jt = 0; jt < 7; ++jt) {
                    U8 b0u, b1u;
                    b0u.u = *(const uint4*)(WL + kt*14336 + jt*2048 + lane*16);
                    b1u.u = *(const uint4*)(WL + kt*14336 + jt*2048 + 1024 + lane*16);
                    #pragma unroll
                    for (int mt = 0; mt < 2; ++mt) {
                        c0[jt][mt] = __builtin_amdgcn_mfma_f32_16x16x32_f16(a0[mt][kt], b0u.h, c0[jt][mt], 0, 0, 0);
                        c1[jt][mt] = __builtin_amdgcn_mfma_f32_16x16x32_f16(a0[mt][kt], b1u.h, c1[jt][mt], 0, 0, 0);
                        c1[jt][mt] = __builtin_amdgcn_mfma_f32_16x16x32_f16(a1[mt][kt], b0u.h, c1[jt][mt], 0, 0, 0);
                    }
                }
            #pragma unroll
            for (int jt = 0; jt < 7; ++jt) {               // K-tail (k=96..99)
                int toff  = (lane < 16) ? (l*LW + 43008 + jt*256 + lane*8) : ZOFF;
                int toff1 = (lane < 16) ? (toff + 128) : ZOFF;
                U4 b0u, b1u;
                b0u.u = *(const uint2*)(smem + toff);
                b1u.u = *(const uint2*)(smem + toff1);
                #pragma unroll
                for (int mt = 0; mt < 2; ++mt) {
                    c0[jt][mt] = __builtin_amdgcn_mfma_f32_16x16x16f16(a0t[mt], b0u.h, c0[jt][mt], 0, 0, 0);
                    c1[jt][mt] = __builtin_amdgcn_mfma_f32_16x16x16f16(a0t[mt], b1u.h, c1[jt][mt], 0, 0, 0);
                    c1[jt][mt] = __builtin_amdgcn_mfma_f32_16x16x16f16(a1t[mt], b0u.h, c1[jt][mt], 0, 0, 0);
                }
            }

            if (l < 2) {
                // ---- transition: two 16-row half-passes per kc tile ----
                #pragma unroll
                for (int kc = 0; kc < 4; ++kc) {
                    int njt = (kc < 3) ? 2 : 1;
                    #pragma unroll
                    for (int mtt = 0; mtt < 2; ++mtt) {
                        #pragma unroll
                        for (int jj = 0; jj < 2; ++jj) {
                            if (jj >= njt) continue;
                            int jt = 2 * kc + jj;
                            int kk = 16 * jj + c15;
                            int j  = 16 * jt + c15;
                            float bj = BL[(j < 100) ? j : 99];
                            float z0 = c0[jt][mtt][0] + c1[jt][mtt][0] * (1.0f/512.0f) + bj;
                            float z1 = c0[jt][mtt][1] + c1[jt][mtt][1] * (1.0f/512.0f);
                            float z2 = c0[jt][mtt][2] + c1[jt][mtt][2] * (1.0f/512.0f);
                            float z3 = c0[jt][mtt][3] + c1[jt][mtt][3] * (1.0f/512.0f);
                            float a = fast_tanh(z0);
                            float s = 1.0f - a * a;
                            float v[4];
                            v[0] = a; v[1] = s * z1; v[2] = s * z2;
                            v[3] = fmaf(-2.0f * a * s * z2, z2, s * z3);
                            #pragma unroll
                            for (int r = 0; r < 4; ++r) {
                                _Float16 h0, h1; split2(v[r], h0, h1);
                                _Float16* bp = (_Float16*)(stg) + (4 * q + r) * 40 + kk;
                                bp[0]   = h0;
                                bp[640] = h1;    // plane 1 (+1280 B)
                            }
                        }
                        // read this half's A-frags for kt = kc (wave-private)
                        if (kc < 3) {
                            const char* rb = stg + c15 * 80 + 16 * q;
                            U8 u;
                            u.u = *(const uint4*)(rb);            a0[mtt][kc] = u.h;
                            u.u = *(const uint4*)(rb + PLANEB);   a1[mtt][kc] = u.h;
                        } else {
                            U4 u;
                            if (q == 0) {
                                const char* rb = stg + c15 * 80;
                                u.u = *(const uint2*)(rb);            a0t[mtt] = u.h;
                                u.u = *(const uint2*)(rb + PLANEB);   a1t[mtt] = u.h;
                            } else {
                                a0t[mtt] = (half4){0,0,0,0}; a1t[mtt] = (half4){0,0,0,0};
                            }
                        }
                    }
                }
            } else {
                // ---- layer-4 bias+nonlinearity + layer-5 + NLS residual ----
                #pragma unroll
                for (int mt = 0; mt < 2; ++mt) {
                    float p00 = 0.f, p01 = 0.f, p03 = 0.f;   // W5 row 0 (real)
                    float p10 = 0.f, p11 = 0.f, p13 = 0.f;   // W5 row 1 (imag)
                    #pragma unroll
                    for (int jt = 0; jt < 7; ++jt) {
                        int j = 16 * jt + c15;
                        int j2 = (j < 100) ? j : 99;
                        float m = (j < 100) ? 1.0f : 0.0f;
                        float bj = BL[j2];
                        float w50 = W5[j2] * m, w51 = W5[100 + j2] * m;
                        float z0 = c0[jt][mt][0] + c1[jt][mt][0] * (1.0f/512.0f) + bj;
                        float z1 = c0[jt][mt][1] + c1[jt][mt][1] * (1.0f/512.0f);
                        float z2 = c0[jt][mt][2] + c1[jt][mt][2] * (1.0f/512.0f);
                        float z3 = c0[jt][mt][3] + c1[jt][mt][3] * (1.0f/512.0f);
                        float a = fast_tanh(z0);
                        float s = 1.0f - a * a;
                        float v0 = a, v1 = s * z1;
                        float v3 = fmaf(-2.0f * a * s * z2, z2, s * z3);
                        p00 = fmaf(w50, v0, p00);
                        p01 = fmaf(w50, v1, p01);
                        p03 = fmaf(w50, v3, p03);
                        p10 = fmaf(w51, v0, p10);
                        p11 = fmaf(w51, v1, p11);
                        p13 = fmaf(w51, v3, p13);
                    }
                    #pragma unroll
                    for (int m = 1; m <= 8; m <<= 1) {
                        p00 += __shfl_xor(p00, m, 64);
                        p01 += __shfl_xor(p01, m, 64);
                        p03 += __shfl_xor(p03, m, 64);
                        p10 += __shfl_xor(p10, m, 64);
                        p11 += __shfl_xor(p11, m, 64);
                        p13 += __shfl_xor(p13, m, 64);
                    }
                    int pt = chunk * 64 + w * 8 + 4 * mt + q;
                    if (c15 == 0 && pt < N) {
                        float ur = p00 + b5[0], ui = p10 + b5[1];
                        float mag2 = ur * ur + ui * ui;
                        float fr = fmaf(mag2, ur, fmaf(0.5f, p03, -p11));
                        float fi = fmaf(mag2, ui, fmaf(0.5f, p13,  p01));
                        out[pt]     = fr;
                        out[N + pt] = fi;
                    }
                }
            }
        }
    }
}

extern "C" void kernel_launch(void* const* d_in, const int* in_sizes, int n_in,
                              void* d_out, int out_size, void* d_ws, size_t ws_size,
                              hipStream_t stream) {
    const float* x  = (const float*)d_in[0];
    const float* t  = (const float*)d_in[1];
    const float* W1 = (const float*)d_in[2];
    const float* b1 = (const float*)d_in[3];
    const float* W2 = (const float*)d_in[4];
    const float* b2 = (const float*)d_in[5];
    const float* W3 = (const float*)d_in[6];
    const float* b3 = (const float*)d_in[7];
    const float* W4 = (const float*)d_in[8];
    const float* b4 = (const float*)d_in[9];
    const float* W5 = (const float*)d_in[10];
    const float* b5 = (const float*)d_in[11];
    float* out = (float*)d_out;
    const int N = in_sizes[0];
    const int nchunks = (N + 63) / 64;       // 256 cols = 64 points per chunk

    (void)hipFuncSetAttribute((const void*)pinn_mfma,
                              hipFuncAttributeMaxDynamicSharedMemorySize, SMEM_BYTES);

    prep_w<<<84, 64, 0, stream>>>(W2, W3, W4, (unsigned short*)d_ws);
    pinn_mfma<<<256, 512, SMEM_BYTES, stream>>>(x, t, W1, b1, b2, b3, b4, W5, b5,
                                                (const char*)d_ws, out, N, nchunks);
}